// Round 8
// baseline (702.053 us; speedup 1.0000x reference)
//
#include <hip/hip_runtime.h>
#include <hip/hip_bf16.h>
#include <hip/hip_fp16.h>
#include <stdint.h>

#define N_NODES 100000
#define IN_CH   128
#define HID     128
#define OUT_CH  64
#define N_EDGES 1600000

#define NB    196      // buckets of 512 nodes
#define NBLK  250      // edge-partition blocks for phases A/B
#define EPB   6400     // edges per block

#define SS    ((size_t)N_NODES * 16)   // slice stride in shorts (3.2 MB)

typedef __attribute__((ext_vector_type(8))) short  s16x8;   // 8 f16 for MFMA
typedef __attribute__((ext_vector_type(4))) float  f32x4;

__device__ __forceinline__ __half2 as_h2(unsigned int u) { return *(__half2*)&u; }

// ---------------- CSR build: bucket sort (as R7) ----------------

__global__ __launch_bounds__(256) void k_phaseA(const int* __restrict__ dst,
                                                int* __restrict__ Cm) {
    __shared__ int hist[NB];
    int blk = blockIdx.x, t = threadIdx.x;
    if (t < NB) hist[t] = 0;
    __syncthreads();
    int base = blk * EPB;
#pragma unroll 5
    for (int k = 0; k < EPB / 256; k++) {
        int d = dst[base + k * 256 + t];
        atomicAdd(&hist[d >> 9], 1);
    }
    __syncthreads();
    if (t < NB) Cm[blk * NB + t] = hist[t];
}

__global__ __launch_bounds__(256) void k_scanBkt(int* __restrict__ Cm,
                                                 int* __restrict__ bktSum) {
    __shared__ int sdata[256];
    int b = blockIdx.x, t = threadIdx.x;
    int v = (t < NBLK) ? Cm[t * NB + b] : 0;
    sdata[t] = v;
    __syncthreads();
    int val = v;
    for (int off = 1; off < 256; off <<= 1) {
        int tmp = (t >= off) ? sdata[t - off] : 0;
        __syncthreads();
        val += tmp;
        sdata[t] = val;
        __syncthreads();
    }
    if (t < NBLK) Cm[t * NB + b] = val - v;
    if (t == 255) bktSum[b] = val;
}

__global__ __launch_bounds__(256) void k_scanBase(const int* __restrict__ bktSum,
                                                  int* __restrict__ bktBase) {
    __shared__ int sdata[256];
    int t = threadIdx.x;
    int v = (t < NB) ? bktSum[t] : 0;
    sdata[t] = v;
    __syncthreads();
    int val = v;
    for (int off = 1; off < 256; off <<= 1) {
        int tmp = (t >= off) ? sdata[t - off] : 0;
        __syncthreads();
        val += tmp;
        sdata[t] = val;
        __syncthreads();
    }
    if (t < NB) bktBase[t] = val - v;
    if (t == 0) bktBase[NB] = N_EDGES;
}

__global__ __launch_bounds__(256) void k_phaseB(const int* __restrict__ src,
                                                const int* __restrict__ dst,
                                                const int* __restrict__ Cm,
                                                const int* __restrict__ bktBase,
                                                unsigned int* __restrict__ bucketed) {
    __shared__ int offs[NB];
    int blk = blockIdx.x, t = threadIdx.x;
    if (t < NB) offs[t] = Cm[blk * NB + t] + bktBase[t];
    __syncthreads();
    int base = blk * EPB;
#pragma unroll 5
    for (int k = 0; k < EPB / 256; k++) {
        int e = base + k * 256 + t;
        int d = dst[e];
        int sv = src[e];
        int pos = atomicAdd(&offs[d >> 9], 1);
        bucketed[pos] = ((unsigned int)sv << 9) | (unsigned int)(d & 511);
    }
}

__global__ __launch_bounds__(512) void k_phaseC(const unsigned int* __restrict__ bucketed,
                                                const int* __restrict__ bktBase,
                                                int* __restrict__ rowptr,
                                                float* __restrict__ dinvg,
                                                unsigned int* __restrict__ dinvh2,
                                                int* __restrict__ csr_src) {
    __shared__ int cnt[512];
    __shared__ int cur[512];
    __shared__ int sdata[512];
    int b = blockIdx.x, t = threadIdx.x;
    int base = bktBase[b], endR = bktBase[b + 1];
    int nodeBase = b << 9;
    int nNodes = N_NODES - nodeBase;
    if (nNodes > 512) nNodes = 512;

    cnt[t] = 0;
    __syncthreads();
    for (int e = base + t; e < endR; e += 512)
        atomicAdd(&cnt[bucketed[e] & 511], 1);
    __syncthreads();

    int s = cnt[t];
    sdata[t] = s;
    __syncthreads();
    int val = s;
    for (int off = 1; off < 512; off <<= 1) {
        int tmp = (t >= off) ? sdata[t - off] : 0;
        __syncthreads();
        val += tmp;
        sdata[t] = val;
        __syncthreads();
    }
    cur[t] = val - s;
    if (t < nNodes) {
        rowptr[nodeBase + t] = base + val - s;
        float dv = rsqrtf((float)s + 1.0f);
        dinvg[nodeBase + t] = dv;
        __half hd = __float2half(dv);
        unsigned int hu = *(unsigned short*)&hd;
        dinvh2[nodeBase + t] = hu | (hu << 16);
    }
    if (b == NB - 1 && t == 0) rowptr[N_NODES] = N_EDGES;
    __syncthreads();

    for (int e = base + t; e < endR; e += 512) {
        unsigned int u = bucketed[e];
        int pos = base + atomicAdd(&cur[u & 511], 1);
        csr_src[pos] = (int)(u >> 9);
    }
}

// ---------------- W prep: transpose to f16 [n][k], fuse mu|ls concat --------

__global__ __launch_bounds__(256) void k_prepW(const float* __restrict__ W1,
                                               const float* __restrict__ Wmu,
                                               const float* __restrict__ Wls,
                                               unsigned short* __restrict__ Wt1,
                                               unsigned short* __restrict__ WtC) {
    int idx = blockIdx.x * 256 + threadIdx.x;
    int n = idx >> 7, k = idx & 127;
    __half a = __float2half(W1[k * 128 + n]);
    __half b = __float2half((n < 64) ? Wmu[k * 64 + n] : Wls[k * 64 + (n - 64)]);
    Wt1[idx] = *(unsigned short*)&a;
    WtC[idx] = *(unsigned short*)&b;
}

// ---------------- MFMA GEMMs (f16, K=128), 128-row blocks -------------------
// Output written in SLICED layout: Y[slice][node][16ch], slice == nt.

#define LDA 136

__device__ __forceinline__ void gemm_core(const unsigned short* sA,
                                          const unsigned short* __restrict__ Wt,
                                          unsigned short* __restrict__ Y,
                                          int R0, int t) {
    int wv = t >> 6, l = t & 63;
    int quad = l >> 4, lm = l & 15;

    s16x8 a[2][4];
#pragma unroll
    for (int mt = 0; mt < 2; mt++)
#pragma unroll
        for (int ks = 0; ks < 4; ks++)
            a[mt][ks] = *(const s16x8*)(sA + (wv * 32 + mt * 16 + lm) * LDA +
                                        ks * 32 + quad * 8);

    f32x4 acc[2][8] = {};
#pragma unroll
    for (int nt = 0; nt < 8; nt++) {
        s16x8 b[4];
        const unsigned short* Wp = Wt + (nt * 16 + lm) * 128 + quad * 8;
#pragma unroll
        for (int ks = 0; ks < 4; ks++)
            b[ks] = *(const s16x8*)(Wp + ks * 32);
#pragma unroll
        for (int mt = 0; mt < 2; mt++) {
            f32x4 c = acc[mt][nt];
#pragma unroll
            for (int ks = 0; ks < 4; ks++)
                c = __builtin_amdgcn_mfma_f32_16x16x32_f16(a[mt][ks], b[ks], c, 0, 0, 0);
            acc[mt][nt] = c;
        }
    }

    int rbase = R0 + wv * 32 + quad * 4;
#pragma unroll
    for (int mt = 0; mt < 2; mt++)
#pragma unroll
        for (int nt = 0; nt < 8; nt++)
#pragma unroll
            for (int reg = 0; reg < 4; reg++) {
                int r = rbase + mt * 16 + reg;
                if (r < N_NODES) {
                    __half hv = __float2half(acc[mt][nt][reg]);
                    Y[(size_t)nt * SS + (size_t)r * 16 + lm] = *(unsigned short*)&hv;
                }
            }
}

__global__ __launch_bounds__(256) void k_gemm1(const float* __restrict__ X,
                                               const unsigned short* __restrict__ Wt,
                                               unsigned short* __restrict__ Y) {
    __shared__ unsigned short sA[128 * LDA];
    int t = threadIdx.x;
    int R0 = blockIdx.x * 128;
    int row = t >> 1, colb = (t & 1) * 64;
    bool valid = (R0 + row) < N_NODES;
    const float* Xr = X + (size_t)(R0 + row) * 128 + colb;
    unsigned short* dp = sA + row * LDA + colb;
#pragma unroll
    for (int j = 0; j < 16; j++) {
        float4 v = valid ? *(const float4*)(Xr + j * 4) : make_float4(0.f, 0.f, 0.f, 0.f);
        __half2 p0 = __floats2half2_rn(v.x, v.y);
        __half2 p1 = __floats2half2_rn(v.z, v.w);
        uint2 o;
        o.x = *(unsigned int*)&p0;
        o.y = *(unsigned int*)&p1;
        *(uint2*)(dp + j * 4) = o;
    }
    __syncthreads();
    gemm_core(sA, Wt, Y, R0, t);
}

// staging from sliced f16 input: slice-major for full coalescing
__global__ __launch_bounds__(256) void k_gemm2(const unsigned short* __restrict__ Xs,
                                               const unsigned short* __restrict__ Wt,
                                               unsigned short* __restrict__ Y) {
    __shared__ unsigned short sA[128 * LDA];
    int t = threadIdx.x;
    int R0 = blockIdx.x * 128;
    int q = t >> 5;                 // slice 0..7
    int sub = t & 31;               // 32 threads per slice
    int part = (sub & 1) * 8;       // half-row (8 shorts)
#pragma unroll
    for (int rr = 0; rr < 8; rr++) {
        int row = rr * 16 + (sub >> 1);
        int gr = R0 + row;
        uint4 v = (gr < N_NODES)
                      ? *(const uint4*)(Xs + (size_t)q * SS + (size_t)gr * 16 + part)
                      : make_uint4(0u, 0u, 0u, 0u);
        *(uint4*)(sA + row * LDA + q * 16 + part) = v;
    }
    __syncthreads();
    gemm_core(sA, Wt, Y, R0, t);
}

// ---- sliced agg gather: slice = blockIdx&7 (XCD-pinned via %8 round-robin),
// wave = 1 node, 8 groups x 8 lanes, group g takes edge p+g; unroll 2.
// Returns per-lane (l<8) float2 = 2 channels of slice. ----

__device__ __forceinline__ float2 agg_gather_sl(const unsigned short* __restrict__ tb,
                                                const int* __restrict__ rowptr,
                                                const int* __restrict__ csr_src,
                                                const unsigned int* __restrict__ dh2,
                                                const float* __restrict__ dinv,
                                                int i, int l) {
    int g = l >> 3;          // edge subgroup 0..7
    int cl = l & 7;          // channel pair within slice
    float di = dinv[i];
    unsigned int sv = *(const unsigned int*)(tb + (size_t)i * 16 + cl * 2);
    __half2 acc = __floats2half2_rn(0.f, 0.f);
    int beg = rowptr[i], end = rowptr[i + 1];
    for (int p = beg; p < end; p += 16) {
        int q0 = p + g, q1 = p + 8 + g;
        int s0 = __builtin_nontemporal_load(csr_src + (q0 < end ? q0 : end - 1));
        int s1 = __builtin_nontemporal_load(csr_src + (q1 < end ? q1 : end - 1));
        unsigned int n0 = dh2[s0];
        unsigned int n1 = dh2[s1];
        unsigned int r0 = *(const unsigned int*)(tb + (size_t)s0 * 16 + cl * 2);
        unsigned int r1 = *(const unsigned int*)(tb + (size_t)s1 * 16 + cl * 2);
        n0 = (q0 < end) ? n0 : 0u;
        n1 = (q1 < end) ? n1 : 0u;
        acc = __hfma2(as_h2(r0), as_h2(n0), acc);
        acc = __hfma2(as_h2(r1), as_h2(n1), acc);
    }
    // combine the 8 groups (butterfly over lane bits 3,4,5)
#pragma unroll
    for (int m = 8; m <= 32; m <<= 1) {
        int v = *(int*)&acc;
        int u = __shfl_xor(v, m);
        acc = __hadd2(acc, *(__half2*)&u);
    }
    float2 f = __half22float2(acc);
    float2 hs = __half22float2(as_h2(sv));
    f.x = di * f.x + di * di * hs.x;
    f.y = di * f.y + di * di * hs.y;
    return f;
}

// agg1: h = relu(agg(h0)+b1) -> sliced f16
__global__ __launch_bounds__(256) void k_agg1(const unsigned short* __restrict__ h0,
                                              const int* __restrict__ rowptr,
                                              const int* __restrict__ csr_src,
                                              const unsigned int* __restrict__ dh2,
                                              const float* __restrict__ dinv,
                                              const float* __restrict__ b1,
                                              unsigned short* __restrict__ hb) {
    int l = threadIdx.x & 63;
    int wv = threadIdx.x >> 6;
    int slice = blockIdx.x & 7;
    int i = __builtin_amdgcn_readfirstlane((blockIdx.x >> 3) * 4 + wv);
    const unsigned short* tb = h0 + (size_t)slice * SS;
    float2 f = agg_gather_sl(tb, rowptr, csr_src, dh2, dinv, i, l);
    if (l < 8) {
        int c = slice * 16 + l * 2;
        f.x += b1[c];
        f.y += b1[c + 1];
        f.x = f.x > 0.f ? f.x : 0.f;
        f.y = f.y > 0.f ? f.y : 0.f;
        __half2 o = __floats2half2_rn(f.x, f.y);
        *(unsigned int*)(hb + (size_t)slice * SS + (size_t)i * 16 + l * 2) =
            *(unsigned int*)&o;
    }
}

// agg2: out = agg(t) + bias (f32 out; slices 0-3 = mu, 4-7 = logstd)
__global__ __launch_bounds__(256) void k_agg2(const unsigned short* __restrict__ tt,
                                              const int* __restrict__ rowptr,
                                              const int* __restrict__ csr_src,
                                              const unsigned int* __restrict__ dh2,
                                              const float* __restrict__ dinv,
                                              const float* __restrict__ bmu,
                                              const float* __restrict__ bls,
                                              float* __restrict__ out) {
    int l = threadIdx.x & 63;
    int wv = threadIdx.x >> 6;
    int slice = blockIdx.x & 7;
    int i = __builtin_amdgcn_readfirstlane((blockIdx.x >> 3) * 4 + wv);
    const unsigned short* tb = tt + (size_t)slice * SS;
    float2 f = agg_gather_sl(tb, rowptr, csr_src, dh2, dinv, i, l);
    if (l < 8) {
        int c = slice * 16 + l * 2;
        if (c < 64)
            *(float2*)(out + (size_t)i * 64 + c) =
                make_float2(f.x + bmu[c], f.y + bmu[c + 1]);
        else
            *(float2*)(out + (size_t)N_NODES * 64 + (size_t)i * 64 + (c - 64)) =
                make_float2(f.x + bls[c - 64], f.y + bls[c - 63]);
    }
}

// ---------------- launch ----------------

extern "C" void kernel_launch(void* const* d_in, const int* in_sizes, int n_in,
                              void* d_out, int out_size, void* d_ws, size_t ws_size,
                              hipStream_t stream) {
    const float* x    = (const float*)d_in[0];
    const int*   ei   = (const int*)d_in[1];
    const float* W1   = (const float*)d_in[2];
    const float* b1   = (const float*)d_in[3];
    const float* Wmu  = (const float*)d_in[4];
    const float* bmu  = (const float*)d_in[5];
    const float* Wls  = (const float*)d_in[6];
    const float* bls  = (const float*)d_in[7];
    const int* src = ei;
    const int* dst = ei + N_EDGES;

    char* p = (char*)d_ws;
    unsigned short* bufA = (unsigned short*)p; p += (size_t)N_NODES * 128 * 2; // h0 / t (sliced f16)
    unsigned short* bufH = (unsigned short*)p; p += (size_t)N_NODES * 128 * 2; // h (sliced f16)
    unsigned short* Wt1  = (unsigned short*)p; p += 128 * 128 * 2;
    unsigned short* WtC  = (unsigned short*)p; p += 128 * 128 * 2;
    int*   Cm      = (int*)p;   p += (size_t)NBLK * NB * 4;
    int*   bktSum  = (int*)p;   p += 256 * 4;
    int*   bktBase = (int*)p;   p += 256 * 4;
    int*   rowptr  = (int*)p;   p += 400016;
    float* dinv    = (float*)p; p += 400000;
    unsigned int* dinvh2 = (unsigned int*)p; p += 400000;
    unsigned int* bucketed = (unsigned int*)p; p += (size_t)N_EDGES * 4;
    int*   csr_src = (int*)p;   p += (size_t)N_EDGES * 4;

    // CSR build
    k_phaseA<<<NBLK, 256, 0, stream>>>(dst, Cm);
    k_scanBkt<<<NB, 256, 0, stream>>>(Cm, bktSum);
    k_scanBase<<<1, 256, 0, stream>>>(bktSum, bktBase);
    k_phaseB<<<NBLK, 256, 0, stream>>>(src, dst, Cm, bktBase, bucketed);
    k_phaseC<<<NB, 512, 0, stream>>>(bucketed, bktBase, rowptr, dinv, dinvh2, csr_src);

    k_prepW<<<64, 256, 0, stream>>>(W1, Wmu, Wls, Wt1, WtC);

    int gblk = (N_NODES + 127) / 128;     // 782
    int ablk = (N_NODES / 4) * 8;         // 200000: slice = blockIdx & 7

    // layer 1: h0 = x @ W1 (MFMA f16, sliced out) ; h = relu(agg(h0) + b1)
    k_gemm1<<<gblk, 256, 0, stream>>>(x, Wt1, bufA);
    k_agg1<<<ablk, 256, 0, stream>>>(bufA, rowptr, csr_src, dinvh2, dinv, b1, bufH);

    // layer 2: t = h @ [Wmu|Wls] (sliced out) ; out = agg(t) + bias
    k_gemm2<<<gblk, 256, 0, stream>>>(bufH, WtC, bufA);
    k_agg2<<<ablk, 256, 0, stream>>>(bufA, rowptr, csr_src, dinvh2, dinv,
                                     bmu, bls, (float*)d_out);
}

// Round 9
// 452.891 us; speedup vs baseline: 1.5502x; 1.5502x over previous
//
#include <hip/hip_runtime.h>
#include <hip/hip_cooperative_groups.h>
#include <hip/hip_bf16.h>
#include <hip/hip_fp16.h>
#include <stdint.h>

namespace cg = cooperative_groups;

#define N_NODES 100000
#define IN_CH   128
#define HID     128
#define OUT_CH  64
#define N_EDGES 1600000

#define NB    196      // buckets of 512 nodes
#define CSRG  250      // cooperative grid blocks (= edge partition blocks)
#define EPB   6400     // edges per block (250*6400 = 1.6M)

typedef __attribute__((ext_vector_type(8))) short  s16x8;   // 8 f16 for MFMA
typedef __attribute__((ext_vector_type(4))) float  f32x4;

__device__ __forceinline__ __half2 as_h2(unsigned int u) { return *(__half2*)&u; }

// ============ fused CSR build + W prep (ONE cooperative kernel) ============
// phase0: W transpose->f16. phaseA: per-block bucket histogram (+global
// bucket totals via atomics). scan: per-bucket exclusive prefix over blocks
// + redundant per-block scan of bucket totals into LDS. phaseB: scatter
// edges into bucket regions (pre-reserved -> full-line writebacks).
// phaseC: per-bucket counting sort -> rowptr/dinv/csr_src.

__global__ __launch_bounds__(256) void k_csr(
    const float* __restrict__ W1, const float* __restrict__ Wmu,
    const float* __restrict__ Wls,
    unsigned short* __restrict__ Wt1, unsigned short* __restrict__ WtC,
    const int* __restrict__ src, const int* __restrict__ dst,
    int* __restrict__ Cm, int* __restrict__ bktSum,
    unsigned int* __restrict__ bucketed,
    int* __restrict__ rowptr, float* __restrict__ dinvg,
    unsigned int* __restrict__ dinvh2, int* __restrict__ csr_src)
{
    cg::grid_group grid = cg::this_grid();
    __shared__ int hist[NB];
    __shared__ int sdata[256];
    __shared__ int ldsBase[NB + 1];
    __shared__ int offs[NB];
    __shared__ int cnt[512];
    __shared__ int cur2[512];

    int blk = blockIdx.x, t = threadIdx.x;
    int base = blk * EPB;

    // ---- phase 0: prepW (16384 elems over 64000 threads) ----
    int gid = blk * 256 + t;
    if (gid < 128 * 128) {
        int n = gid >> 7, k = gid & 127;
        __half a = __float2half(W1[k * 128 + n]);
        __half b = __float2half((n < 64) ? Wmu[k * 64 + n] : Wls[k * 64 + (n - 64)]);
        Wt1[gid] = *(unsigned short*)&a;
        WtC[gid] = *(unsigned short*)&b;
    }

    // ---- phase A: histogram ----
    if (t < NB) hist[t] = 0;
    __syncthreads();
#pragma unroll 5
    for (int k = 0; k < EPB / 256; k++) {
        int d = dst[base + k * 256 + t];
        atomicAdd(&hist[d >> 9], 1);
    }
    __syncthreads();
    if (t < NB) {
        int h = hist[t];
        Cm[blk * NB + t] = h;
        atomicAdd(&bktSum[t], h);   // bktSum pre-zeroed by memset
    }
    grid.sync();

    // ---- scan (a): exclusive prefix of Cm[:,b] over blocks, b = blk ----
    {
        int v = (blk < NB && t < CSRG) ? Cm[t * NB + blk] : 0;
        sdata[t] = v;
        __syncthreads();
        int val = v;
        for (int off = 1; off < 256; off <<= 1) {
            int tmp = (t >= off) ? sdata[t - off] : 0;
            __syncthreads();
            val += tmp;
            sdata[t] = val;
            __syncthreads();
        }
        if (blk < NB && t < CSRG) Cm[t * NB + blk] = val - v;
    }
    __syncthreads();
    // ---- scan (b): redundant per-block scan of bucket totals -> ldsBase ----
    {
        int v = (t < NB) ? bktSum[t] : 0;
        sdata[t] = v;
        __syncthreads();
        int val = v;
        for (int off = 1; off < 256; off <<= 1) {
            int tmp = (t >= off) ? sdata[t - off] : 0;
            __syncthreads();
            val += tmp;
            sdata[t] = val;
            __syncthreads();
        }
        if (t < NB) ldsBase[t] = val - v;
        if (t == 0) ldsBase[NB] = N_EDGES;
    }
    grid.sync();

    // ---- phase B: scatter edges into bucket regions ----
    if (t < NB) offs[t] = Cm[blk * NB + t] + ldsBase[t];
    __syncthreads();
#pragma unroll 5
    for (int k = 0; k < EPB / 256; k++) {
        int e = base + k * 256 + t;
        int d = dst[e];
        int sv = src[e];
        int pos = atomicAdd(&offs[d >> 9], 1);
        bucketed[pos] = ((unsigned int)sv << 9) | (unsigned int)(d & 511);
    }
    grid.sync();

    // ---- phase C: per-bucket counting sort (blocks 0..NB-1) ----
    if (blk < NB) {
        int b = blk;
        int base2 = ldsBase[b], endR = ldsBase[b + 1];
        int nodeBase = b << 9;
        int nNodes = N_NODES - nodeBase;
        if (nNodes > 512) nNodes = 512;

        cnt[t] = 0;
        cnt[t + 256] = 0;
        __syncthreads();
        for (int e = base2 + t; e < endR; e += 256)
            atomicAdd(&cnt[bucketed[e] & 511], 1);
        __syncthreads();

        int s0 = cnt[2 * t], s1 = cnt[2 * t + 1];
        int s = s0 + s1;
        sdata[t] = s;
        __syncthreads();
        int val = s;
        for (int off = 1; off < 256; off <<= 1) {
            int tmp = (t >= off) ? sdata[t - off] : 0;
            __syncthreads();
            val += tmp;
            sdata[t] = val;
            __syncthreads();
        }
        int excl = val - s;
        cur2[2 * t] = excl;
        cur2[2 * t + 1] = excl + s0;
        if (2 * t < nNodes) {
            rowptr[nodeBase + 2 * t] = base2 + excl;
            float dv = rsqrtf((float)s0 + 1.0f);
            dinvg[nodeBase + 2 * t] = dv;
            __half hd = __float2half(dv);
            unsigned int hu = *(unsigned short*)&hd;
            dinvh2[nodeBase + 2 * t] = hu | (hu << 16);
        }
        if (2 * t + 1 < nNodes) {
            rowptr[nodeBase + 2 * t + 1] = base2 + excl + s0;
            float dv = rsqrtf((float)s1 + 1.0f);
            dinvg[nodeBase + 2 * t + 1] = dv;
            __half hd = __float2half(dv);
            unsigned int hu = *(unsigned short*)&hd;
            dinvh2[nodeBase + 2 * t + 1] = hu | (hu << 16);
        }
        if (b == NB - 1 && t == 0) rowptr[N_NODES] = N_EDGES;
        __syncthreads();

        for (int e = base2 + t; e < endR; e += 256) {
            unsigned int u = bucketed[e];
            int pos = base2 + atomicAdd(&cur2[u & 511], 1);
            csr_src[pos] = (int)(u >> 9);
        }
    }
}

// ---------------- MFMA GEMMs (f16, K=128), 128-row blocks (R7) --------------

#define LDA 136

__device__ __forceinline__ void gemm_core(const unsigned short* sA,
                                          const unsigned short* __restrict__ Wt,
                                          unsigned short* __restrict__ Y,
                                          int R0, int t) {
    int wv = t >> 6, l = t & 63;
    int quad = l >> 4, lm = l & 15;

    s16x8 a[2][4];
#pragma unroll
    for (int mt = 0; mt < 2; mt++)
#pragma unroll
        for (int ks = 0; ks < 4; ks++)
            a[mt][ks] = *(const s16x8*)(sA + (wv * 32 + mt * 16 + lm) * LDA +
                                        ks * 32 + quad * 8);

    f32x4 acc[2][8] = {};
#pragma unroll
    for (int nt = 0; nt < 8; nt++) {
        s16x8 b[4];
        const unsigned short* Wp = Wt + (nt * 16 + lm) * 128 + quad * 8;
#pragma unroll
        for (int ks = 0; ks < 4; ks++)
            b[ks] = *(const s16x8*)(Wp + ks * 32);
#pragma unroll
        for (int mt = 0; mt < 2; mt++) {
            f32x4 c = acc[mt][nt];
#pragma unroll
            for (int ks = 0; ks < 4; ks++)
                c = __builtin_amdgcn_mfma_f32_16x16x32_f16(a[mt][ks], b[ks], c, 0, 0, 0);
            acc[mt][nt] = c;
        }
    }

    int rbase = R0 + wv * 32 + quad * 4;
#pragma unroll
    for (int mt = 0; mt < 2; mt++)
#pragma unroll
        for (int nt = 0; nt < 8; nt++)
#pragma unroll
            for (int reg = 0; reg < 4; reg++) {
                int r = rbase + mt * 16 + reg;
                if (r < N_NODES) {
                    __half hv = __float2half(acc[mt][nt][reg]);
                    Y[(size_t)r * 128 + nt * 16 + lm] = *(unsigned short*)&hv;
                }
            }
}

__global__ __launch_bounds__(256) void k_gemm1(const float* __restrict__ X,
                                               const unsigned short* __restrict__ Wt,
                                               unsigned short* __restrict__ Y) {
    __shared__ unsigned short sA[128 * LDA];
    int t = threadIdx.x;
    int R0 = blockIdx.x * 128;
    int row = t >> 1, colb = (t & 1) * 64;
    bool valid = (R0 + row) < N_NODES;
    const float* Xr = X + (size_t)(R0 + row) * 128 + colb;
    unsigned short* dp = sA + row * LDA + colb;
#pragma unroll
    for (int j = 0; j < 16; j++) {
        float4 v = valid ? *(const float4*)(Xr + j * 4) : make_float4(0.f, 0.f, 0.f, 0.f);
        __half2 p0 = __floats2half2_rn(v.x, v.y);
        __half2 p1 = __floats2half2_rn(v.z, v.w);
        uint2 o;
        o.x = *(unsigned int*)&p0;
        o.y = *(unsigned int*)&p1;
        *(uint2*)(dp + j * 4) = o;
    }
    __syncthreads();
    gemm_core(sA, Wt, Y, R0, t);
}

__global__ __launch_bounds__(256) void k_gemm2(const unsigned short* __restrict__ Xh,
                                               const unsigned short* __restrict__ Wt,
                                               unsigned short* __restrict__ Y) {
    __shared__ unsigned short sA[128 * LDA];
    int t = threadIdx.x;
    int R0 = blockIdx.x * 128;
    int row = t >> 1, colb = (t & 1) * 64;
    bool valid = (R0 + row) < N_NODES;
    const unsigned short* Xr = Xh + (size_t)(R0 + row) * 128 + colb;
    unsigned short* dp = sA + row * LDA + colb;
#pragma unroll
    for (int j = 0; j < 8; j++) {
        uint4 v = valid ? *(const uint4*)(Xr + j * 8) : make_uint4(0u, 0u, 0u, 0u);
        *(uint4*)(dp + j * 8) = v;
    }
    __syncthreads();
    gemm_core(sA, Wt, Y, R0, t);
}

// ---- agg gather core (R7): wave = 1 node, 2 ch/lane, dword gathers, x8 ----

__device__ __forceinline__ float2 agg_gather(const unsigned short* __restrict__ tbl,
                                             const int* __restrict__ rowptr,
                                             const int* __restrict__ csr_src,
                                             const unsigned int* __restrict__ dh2,
                                             const float* __restrict__ dinv,
                                             int i, int c2) {
    float di = dinv[i];
    unsigned int sv = *(const unsigned int*)(tbl + (size_t)i * 128 + c2);
    __half2 acc = __floats2half2_rn(0.f, 0.f);
    int beg = rowptr[i], end = rowptr[i + 1];
    for (int p = beg; p < end; p += 8) {
        int s[8]; unsigned int nv[8]; unsigned int r[8];
#pragma unroll
        for (int j = 0; j < 8; j++) {
            int q = p + j;
            s[j] = csr_src[q < end ? q : end - 1];
        }
#pragma unroll
        for (int j = 0; j < 8; j++) nv[j] = dh2[s[j]];
#pragma unroll
        for (int j = 0; j < 8; j++)
            r[j] = *(const unsigned int*)(tbl + (size_t)s[j] * 128 + c2);
#pragma unroll
        for (int j = 0; j < 8; j++) {
            unsigned int nn = (p + j < end) ? nv[j] : 0u;
            acc = __hfma2(as_h2(r[j]), as_h2(nn), acc);
        }
    }
    float2 f = __half22float2(acc);
    float2 hs = __half22float2(as_h2(sv));
    f.x = di * f.x + di * di * hs.x;
    f.y = di * f.y + di * di * hs.y;
    return f;
}

__global__ __launch_bounds__(256) void k_agg1(const unsigned short* __restrict__ h0,
                                              const int* __restrict__ rowptr,
                                              const int* __restrict__ csr_src,
                                              const unsigned int* __restrict__ dh2,
                                              const float* __restrict__ dinv,
                                              const float* __restrict__ b1,
                                              unsigned short* __restrict__ hb) {
    int lane = threadIdx.x & 63;
    int i = __builtin_amdgcn_readfirstlane(blockIdx.x * 4 + (threadIdx.x >> 6));
    int c2 = lane * 2;
    float2 f = agg_gather(h0, rowptr, csr_src, dh2, dinv, i, c2);
    f.x += b1[c2];
    f.y += b1[c2 + 1];
    f.x = f.x > 0.f ? f.x : 0.f;
    f.y = f.y > 0.f ? f.y : 0.f;
    __half2 o = __floats2half2_rn(f.x, f.y);
    *(unsigned int*)(hb + (size_t)i * 128 + c2) = *(unsigned int*)&o;
}

__global__ __launch_bounds__(256) void k_agg2(const unsigned short* __restrict__ tt,
                                              const int* __restrict__ rowptr,
                                              const int* __restrict__ csr_src,
                                              const unsigned int* __restrict__ dh2,
                                              const float* __restrict__ dinv,
                                              const float* __restrict__ bmu,
                                              const float* __restrict__ bls,
                                              float* __restrict__ out) {
    int lane = threadIdx.x & 63;
    int i = __builtin_amdgcn_readfirstlane(blockIdx.x * 4 + (threadIdx.x >> 6));
    int c2 = lane * 2;
    float2 f = agg_gather(tt, rowptr, csr_src, dh2, dinv, i, c2);
    if (lane < 32) {
        int c = c2;                       // mu channels 0..63
        *(float2*)(out + (size_t)i * 64 + c) =
            make_float2(f.x + bmu[c], f.y + bmu[c + 1]);
    } else {
        int c = c2 - 64;                  // logstd channels 0..63
        *(float2*)(out + (size_t)N_NODES * 64 + (size_t)i * 64 + c) =
            make_float2(f.x + bls[c], f.y + bls[c + 1]);
    }
}

// ---------------- launch ----------------

extern "C" void kernel_launch(void* const* d_in, const int* in_sizes, int n_in,
                              void* d_out, int out_size, void* d_ws, size_t ws_size,
                              hipStream_t stream) {
    const float* x    = (const float*)d_in[0];
    const int*   ei   = (const int*)d_in[1];
    const float* W1   = (const float*)d_in[2];
    const float* b1   = (const float*)d_in[3];
    const float* Wmu  = (const float*)d_in[4];
    const float* bmu  = (const float*)d_in[5];
    const float* Wls  = (const float*)d_in[6];
    const float* bls  = (const float*)d_in[7];
    const int* src = ei;
    const int* dst = ei + N_EDGES;

    char* p = (char*)d_ws;
    unsigned short* bufA = (unsigned short*)p; p += (size_t)N_NODES * 128 * 2; // h0 / t (f16)
    unsigned short* bufH = (unsigned short*)p; p += (size_t)N_NODES * 128 * 2; // h (f16)
    unsigned short* Wt1  = (unsigned short*)p; p += 128 * 128 * 2;
    unsigned short* WtC  = (unsigned short*)p; p += 128 * 128 * 2;
    int*   Cm      = (int*)p;   p += (size_t)CSRG * NB * 4;
    int*   bktSum  = (int*)p;   p += 256 * 4;
    int*   rowptr  = (int*)p;   p += 400016;
    float* dinv    = (float*)p; p += 400000;
    unsigned int* dinvh2 = (unsigned int*)p; p += 400000;
    unsigned int* bucketed = (unsigned int*)p; p += (size_t)N_EDGES * 4;
    int*   csr_src = (int*)p;   p += (size_t)N_EDGES * 4;

    hipMemsetAsync(bktSum, 0, NB * sizeof(int), stream);

    // fused CSR build + W prep (cooperative, 3 grid syncs)
    {
        const float *a0 = W1, *a1 = Wmu, *a2 = Wls;
        unsigned short *a3 = Wt1, *a4 = WtC;
        const int *a5 = src, *a6 = dst;
        int *a7 = Cm, *a8 = bktSum;
        unsigned int *a9 = bucketed;
        int *a10 = rowptr;
        float *a11 = dinv;
        unsigned int *a12 = dinvh2;
        int *a13 = csr_src;
        void* args[] = {&a0, &a1, &a2, &a3, &a4, &a5, &a6, &a7, &a8,
                        &a9, &a10, &a11, &a12, &a13};
        hipLaunchCooperativeKernel((const void*)k_csr, dim3(CSRG), dim3(256),
                                   args, 0, stream);
    }

    int gblk = (N_NODES + 127) / 128;   // 782

    // layer 1: h0 = x @ W1 (MFMA f16) ; h = relu(agg(h0) + b1)
    k_gemm1<<<gblk, 256, 0, stream>>>(x, Wt1, bufA);
    k_agg1<<<N_NODES / 4, 256, 0, stream>>>(bufA, rowptr, csr_src, dinvh2, dinv, b1, bufH);

    // layer 2: t = h @ [Wmu|Wls] ; out = agg(t) + bias
    k_gemm2<<<gblk, 256, 0, stream>>>(bufH, WtC, bufA);
    k_agg2<<<N_NODES / 4, 256, 0, stream>>>(bufA, rowptr, csr_src, dinvh2, dinv,
                                            bmu, bls, (float*)d_out);
}